// Round 4
// baseline (188.318 us; speedup 1.0000x reference)
//
#include <hip/hip_runtime.h>
#include <hip/hip_bf16.h>

#define FEATSZ 2048
#define HIDSZ  1024
#define ATTSZ  512
#define BATCH  64
#define FEATN  512

typedef float  f32x4  __attribute__((ext_vector_type(4)));
typedef __bf16 bf16x8 __attribute__((ext_vector_type(8)));

__device__ __forceinline__ unsigned short f2bf(float f) {
    union { float f; unsigned int u; } x; x.f = f;
    unsigned int u = x.u;
    return (unsigned short)((u + 0x7fffu + ((u >> 16) & 1u)) >> 16);
}

// ---------------- K0a: h = key @ wh_w.T + wh_b  (64 x 512) ----------------
__global__ void k_h(const float* __restrict__ key, const float* __restrict__ wh_w,
                    const float* __restrict__ wh_b, float* __restrict__ h) {
    const int b = blockIdx.y;
    const int ac = blockIdx.x;
    const int t = threadIdx.x;         // 256
    const int lane = t & 63, wv = t >> 6;
    float k16[16];
    const float* kb = key + b * HIDSZ;
#pragma unroll
    for (int j = 0; j < 16; ++j) k16[j] = kb[lane + 64 * j];
#pragma unroll 1
    for (int i = 0; i < 16; ++i) {
        int a = ac * 64 + wv * 16 + i;
        const float* wr = wh_w + (size_t)a * HIDSZ;
        float s = 0.f;
#pragma unroll
        for (int j = 0; j < 16; ++j) s += k16[j] * wr[lane + 64 * j];
#pragma unroll
        for (int d = 32; d; d >>= 1) s += __shfl_xor(s, d);
        if (lane == 0) h[b * ATTSZ + a] = s + wh_b[a];
    }
}

// ------- K0b: convert wv_w (512x2048 f32) -> bf16 in MFMA-fragment order -------
__global__ void k_wvcvt(const float* __restrict__ wv_w, unsigned short* __restrict__ wvb) {
    int idx = blockIdx.x * 256 + threadIdx.x;       // < 512*2048
    int a = idx >> 11, k = idx & 2047;
    int CF = a >> 4, c = a & 15, ks = k >> 5, kin = k & 31;
    int lane = c + ((kin >> 3) << 4);
    int dst = ((ks * 32 + CF) * 64 + lane) * 8 + (kin & 7);
    wvb[dst] = f2bf(wv_w[idx]);
}

// ---------------- K1: fused GEMM(feats, wv^T) + tanh·wa -> scores ----------------
// 512 blocks (2/CU), 8 waves, Mtile=64, BK=64, 32 kiters. Wave w owns 64 rows x
// 64 a-cols [w*64,w*64+64) -> disjoint B from L2 (reg dbuf). A staged bf16 by
// reg-staging (glb->cvt->swizzled ds_write_b128); reads conflict-free.
__global__ __launch_bounds__(512, 4) void k_scores(
        const float* __restrict__ feats, const unsigned short* __restrict__ wvb,
        const float* __restrict__ h, const float* __restrict__ wv_b,
        const float* __restrict__ wa, float* __restrict__ scores) {
    __shared__ __align__(16) char smem[2][8192];    // bf16 A dbuf [64 rows][64 k] swizzled
    __shared__ float scp[8][64];
    const int t = threadIdx.x;
    const int lane = t & 63, w = t >> 6;
    const int m0 = blockIdx.x * 64;
    const int b = blockIdx.x >> 3;                  // 8 blocks per batch

    // ---- A staging map: thread t -> row sr=t>>3, 8-bf16 chunk sc=t&7 (of 8)
    const int sr = t >> 3, sc = t & 7;
    const float* gsrc = feats + (size_t)(m0 + sr) * FEATSZ + sc * 8;
    const int swoff = sr * 128 + ((sc ^ (sr & 7)) * 16);   // swizzled byte offset

    auto stconv = [&](int buf, float4 s0, float4 s1) {
        bf16x8 af;
        af[0] = (__bf16)s0.x; af[1] = (__bf16)s0.y; af[2] = (__bf16)s0.z; af[3] = (__bf16)s0.w;
        af[4] = (__bf16)s1.x; af[5] = (__bf16)s1.y; af[6] = (__bf16)s1.z; af[7] = (__bf16)s1.w;
        *(bf16x8*)__builtin_assume_aligned(&smem[buf][swoff], 16) = af;
    };

    // ---- A frag read addrs: row = m*16 + fr, k-chunk = ks*4 + fq, XOR row&7
    const int fr = lane & 15, fq = lane >> 4;
    const int ra0 = fr * 128 + (((0 + fq) ^ (fr & 7)) * 16);   // ks=0
    const int ra1 = fr * 128 + (((4 + fq) ^ (fr & 7)) * 16);   // ks=1

    // ---- B frags (disjoint per wave) from relayout'd wvb (L2-resident)
    const unsigned short* wb = wvb + lane * 8;
    bf16x8 bnA[4];
    auto loadBA = [&](int kk) {
#pragma unroll
        for (int cf = 0; cf < 4; ++cf)
            bnA[cf] = *(const bf16x8*)(wb + (kk * 32 + w * 4 + cf) * 512);
    };

    f32x4 acc[4][4];
#pragma unroll
    for (int m = 0; m < 4; ++m)
#pragma unroll
        for (int cf = 0; cf < 4; ++cf) acc[m][cf] = (f32x4)0.0f;

    // ---- prologue: stage it=0, B kk=0
    {
        float4 s0 = *(const float4*)gsrc;
        float4 s1 = *(const float4*)(gsrc + 4);
        loadBA(0);
        stconv(0, s0, s1);
    }
    __syncthreads();

#pragma unroll 1
    for (int it = 0; it < 32; ++it) {
        const char* ab = &smem[it & 1][0];
        bf16x8 bnB[4];
#pragma unroll
        for (int cf = 0; cf < 4; ++cf)                     // B prefetch ks=1 (issue FIRST)
            bnB[cf] = *(const bf16x8*)(wb + ((2 * it + 1) * 32 + w * 4 + cf) * 512);
        float4 s0, s1;
        if (it < 31) {                                     // A stage loads for it+1
            s0 = *(const float4*)(gsrc + (it + 1) * 64);
            s1 = *(const float4*)(gsrc + (it + 1) * 64 + 4);
        }
        // ks=0 with bnA
        {
            bf16x8 a0 = *(const bf16x8*)__builtin_assume_aligned(ab + 0 * 2048 + ra0, 16);
            bf16x8 a1 = *(const bf16x8*)__builtin_assume_aligned(ab + 1 * 2048 + ra0, 16);
            bf16x8 a2 = *(const bf16x8*)__builtin_assume_aligned(ab + 2 * 2048 + ra0, 16);
            bf16x8 a3 = *(const bf16x8*)__builtin_assume_aligned(ab + 3 * 2048 + ra0, 16);
            __builtin_amdgcn_s_setprio(1);
#pragma unroll
            for (int cf = 0; cf < 4; ++cf) acc[0][cf] = __builtin_amdgcn_mfma_f32_16x16x32_bf16(a0, bnA[cf], acc[0][cf], 0, 0, 0);
#pragma unroll
            for (int cf = 0; cf < 4; ++cf) acc[1][cf] = __builtin_amdgcn_mfma_f32_16x16x32_bf16(a1, bnA[cf], acc[1][cf], 0, 0, 0);
#pragma unroll
            for (int cf = 0; cf < 4; ++cf) acc[2][cf] = __builtin_amdgcn_mfma_f32_16x16x32_bf16(a2, bnA[cf], acc[2][cf], 0, 0, 0);
#pragma unroll
            for (int cf = 0; cf < 4; ++cf) acc[3][cf] = __builtin_amdgcn_mfma_f32_16x16x32_bf16(a3, bnA[cf], acc[3][cf], 0, 0, 0);
            __builtin_amdgcn_s_setprio(0);
        }
        if (it < 31) loadBA(2 * it + 2);                   // B prefetch next kiter ks=0
        // ks=1 with bnB
        {
            bf16x8 a0 = *(const bf16x8*)__builtin_assume_aligned(ab + 0 * 2048 + ra1, 16);
            bf16x8 a1 = *(const bf16x8*)__builtin_assume_aligned(ab + 1 * 2048 + ra1, 16);
            bf16x8 a2 = *(const bf16x8*)__builtin_assume_aligned(ab + 2 * 2048 + ra1, 16);
            bf16x8 a3 = *(const bf16x8*)__builtin_assume_aligned(ab + 3 * 2048 + ra1, 16);
            __builtin_amdgcn_s_setprio(1);
#pragma unroll
            for (int cf = 0; cf < 4; ++cf) acc[0][cf] = __builtin_amdgcn_mfma_f32_16x16x32_bf16(a0, bnB[cf], acc[0][cf], 0, 0, 0);
#pragma unroll
            for (int cf = 0; cf < 4; ++cf) acc[1][cf] = __builtin_amdgcn_mfma_f32_16x16x32_bf16(a1, bnB[cf], acc[1][cf], 0, 0, 0);
#pragma unroll
            for (int cf = 0; cf < 4; ++cf) acc[2][cf] = __builtin_amdgcn_mfma_f32_16x16x32_bf16(a2, bnB[cf], acc[2][cf], 0, 0, 0);
#pragma unroll
            for (int cf = 0; cf < 4; ++cf) acc[3][cf] = __builtin_amdgcn_mfma_f32_16x16x32_bf16(a3, bnB[cf], acc[3][cf], 0, 0, 0);
            __builtin_amdgcn_s_setprio(0);
        }
        if (it < 31) stconv((it + 1) & 1, s0, s1);         // cvt + swizzled ds_write
        __syncthreads();
    }

    // ---- epilogue: p[r] = sum_a tanh(acc + h[b,a] + wv_b[a]) * wa[a]
    const int c16 = lane & 15, q4 = lane >> 4;
    float hreg[4], wreg[4];
#pragma unroll
    for (int cf = 0; cf < 4; ++cf) {
        int a = w * 64 + cf * 16 + c16;
        hreg[cf] = h[b * ATTSZ + a] + wv_b[a];
        wreg[cf] = wa[a];
    }
    float p[4][4];
#pragma unroll
    for (int m = 0; m < 4; ++m)
#pragma unroll
        for (int j = 0; j < 4; ++j) p[m][j] = 0.f;
#pragma unroll
    for (int m = 0; m < 4; ++m)
#pragma unroll
        for (int cf = 0; cf < 4; ++cf)
#pragma unroll
            for (int j = 0; j < 4; ++j)
                p[m][j] += tanhf(acc[m][cf][j] + hreg[cf]) * wreg[cf];
#pragma unroll
    for (int m = 0; m < 4; ++m)
#pragma unroll
        for (int j = 0; j < 4; ++j) {
            float v = p[m][j];
            v += __shfl_xor(v, 1); v += __shfl_xor(v, 2);
            v += __shfl_xor(v, 4); v += __shfl_xor(v, 8);
            p[m][j] = v;
        }
    if (c16 == 0) {
#pragma unroll
        for (int m = 0; m < 4; ++m)
#pragma unroll
            for (int j = 0; j < 4; ++j)
                scp[w][m * 16 + q4 * 4 + j] = p[m][j];
    }
    __syncthreads();
    if (t < 64) {
        float s = 0.f;
#pragma unroll
        for (int ww = 0; ww < 8; ++ww) s += scp[ww][t];
        scores[m0 + t] = s;
    }
}

// ---------------- K2: softmax over N=512 per batch ----------------
__global__ void k_softmax(const float* __restrict__ scores, float* __restrict__ alpha) {
    __shared__ float red[16];
    const int b = blockIdx.x, t = threadIdx.x;     // 512 threads
    const int lane = t & 63, w = t >> 6;
    float s = scores[b * FEATN + t];
    float m = s;
#pragma unroll
    for (int d = 32; d; d >>= 1) m = fmaxf(m, __shfl_xor(m, d));
    if (lane == 0) red[w] = m;
    __syncthreads();
    if (t == 0) {
        float mm = red[0];
        for (int i = 1; i < 8; ++i) mm = fmaxf(mm, red[i]);
        red[8] = mm;
    }
    __syncthreads();
    float e = __expf(s - red[8]);
    float sum = e;
#pragma unroll
    for (int d = 32; d; d >>= 1) sum += __shfl_xor(sum, d);
    if (lane == 0) red[w] = sum;
    __syncthreads();
    if (t == 0) {
        float ss = 0.f;
        for (int i = 0; i < 8; ++i) ss += red[i];
        red[9] = 1.0f / ss;
    }
    __syncthreads();
    alpha[b * FEATN + t] = e * red[9];
}

// ---------------- K3a: partial att_feats over n-slices ----------------
__global__ void k_att_part(const float* __restrict__ feats, const float* __restrict__ alpha,
                           float* __restrict__ part) {
    const int b = blockIdx.x, fc = blockIdx.y, ns = blockIdx.z, t = threadIdx.x;
    const int f0 = fc * 1024 + t * 4;
    const float* fp = feats + (size_t)(b * FEATN + ns * 128) * FEATSZ + f0;
    const float* al = alpha + b * FEATN + ns * 128;
    float4 acc = {0.f, 0.f, 0.f, 0.f};
#pragma unroll 4
    for (int i = 0; i < 128; ++i) {
        float a = al[i];
        float4 v = *(const float4*)(fp + (size_t)i * FEATSZ);
        acc.x += a * v.x; acc.y += a * v.y; acc.z += a * v.z; acc.w += a * v.w;
    }
    *(float4*)(part + ((size_t)ns * BATCH + b) * FEATSZ + f0) = acc;
}

// ---------------- K3b: reduce 4 partials -> att_feats ----------------
__global__ void k_att_red(const float* __restrict__ part, float* __restrict__ out) {
    const int idx = (blockIdx.x * 256 + threadIdx.x) * 4;   // < 131072
    float4 s = *(const float4*)(part + idx);
#pragma unroll
    for (int z = 1; z < 4; ++z) {
        float4 v = *(const float4*)(part + (size_t)z * (BATCH * FEATSZ) + idx);
        s.x += v.x; s.y += v.y; s.z += v.z; s.w += v.w;
    }
    *(float4*)(out + idx) = s;
}

extern "C" void kernel_launch(void* const* d_in, const int* in_sizes, int n_in,
                              void* d_out, int out_size, void* d_ws, size_t ws_size,
                              hipStream_t stream) {
    const float* feats = (const float*)d_in[0];
    const float* key   = (const float*)d_in[1];
    const float* wh_w  = (const float*)d_in[2];
    const float* wh_b  = (const float*)d_in[3];
    const float* wv_w  = (const float*)d_in[4];
    const float* wv_b  = (const float*)d_in[5];
    const float* wa_w  = (const float*)d_in[6];

    float* out_att   = (float*)d_out;                 // 64*2048
    float* out_alpha = out_att + BATCH * FEATSZ;      // 64*512

    char* ws = (char*)d_ws;
    float* h              = (float*)(ws);             // 128 KB
    float* scores         = (float*)(ws + 131072);    // 128 KB
    unsigned short* wvb   = (unsigned short*)(ws + 262144);  // 2 MB (used by K0b/K1)
    float* part           = (float*)(ws + 262144);    // 2 MB (reuses wvb region after K1)

    hipLaunchKernelGGL(k_h,        dim3(8, 64),    dim3(256), 0, stream, key, wh_w, wh_b, h);
    hipLaunchKernelGGL(k_wvcvt,    dim3(4096),     dim3(256), 0, stream, wv_w, wvb);
    hipLaunchKernelGGL(k_scores,   dim3(512),      dim3(512), 0, stream, feats, wvb, h, wv_b, wa_w, scores);
    hipLaunchKernelGGL(k_softmax,  dim3(64),       dim3(512), 0, stream, scores, out_alpha);
    hipLaunchKernelGGL(k_att_part, dim3(64, 2, 4), dim3(256), 0, stream, feats, out_alpha, part);
    hipLaunchKernelGGL(k_att_red,  dim3(128),      dim3(256), 0, stream, part, out_att);
}